// Round 4
// baseline (4752.144 us; speedup 1.0000x reference)
//
#include <hip/hip_runtime.h>
#include <hip/hip_fp16.h>

// Masked LSTM, T=512 B=64 D=512 H=512.
// Phase A: x_proj = inputs @ W_ih^T + (b_ih + b_hh), fp16 MFMA GEMM, fp16 out.
// Phase B: persistent recurrence, 4 WAVES PER BLOCK (one gate each), tiny LDS.
//   8 groups (8 batches) x 32 blocks (16 h-dims). Wave q holds gate-q's 16x512
//   W_hh slice as 64 VGPRs of B-frags; per step each wave MFMAs its gate full-k
//   (4 independent 4-deep sub-chains). Waves 1-3 write partials (128 f32) to
//   LDS; ONE __syncthreads; wave 0 reads them, does the in-lane epilogue,
//   publishes h (sc1 relaxed agent atomics), drains vmcnt, sets the group flag,
//   then issues out[] stores + next x_proj prefetch overlapping the spin.
//   Flag ordering makes part[] reuse race-free (writes happen only after the
//   next spin releases, which requires wave0's flag, which follows its reads).
//   Group g's blocks are blk%8==g -> same XCD (round-robin dispatch): exchange
//   stays L2-local.

#define T_DIM 512
#define B_DIM 64
#define D_DIM 512
#define H_DIM 512
#define G_DIM 2048
#define M_DIM (T_DIM * B_DIM)

#define NGROUP 8
#define BPG 32
#define NBLK (NGROUP * BPG)     // 256

typedef __attribute__((ext_vector_type(8))) _Float16 half8;
typedef __attribute__((ext_vector_type(2))) __fp16 fp16x2;
typedef __attribute__((ext_vector_type(4))) float float4v;

#define AT_LD_U(p)    __hip_atomic_load((p), __ATOMIC_RELAXED, __HIP_MEMORY_SCOPE_AGENT)
#define AT_ST_U(p, v) __hip_atomic_store((p), (v), __ATOMIC_RELAXED, __HIP_MEMORY_SCOPE_AGENT)
#define AT_LD_I(p)    __hip_atomic_load((p), __ATOMIC_RELAXED, __HIP_MEMORY_SCOPE_AGENT)
#define AT_ST_I(p, v) __hip_atomic_store((p), (v), __ATOMIC_RELAXED, __HIP_MEMORY_SCOPE_AGENT)
#define AT_LD64(p)    __hip_atomic_load((p), __ATOMIC_RELAXED, __HIP_MEMORY_SCOPE_AGENT)

__device__ __forceinline__ float sigf(float x) { return 1.0f / (1.0f + __expf(-x)); }
__device__ __forceinline__ float tanhfast(float x) { return 2.0f / (1.0f + __expf(-2.0f * x)) - 1.0f; }
__device__ __forceinline__ unsigned short f2h(float x) {
  return __builtin_bit_cast(unsigned short, (_Float16)x);
}
__device__ __forceinline__ unsigned pk2h(float a, float b) {
  fp16x2 h = __builtin_amdgcn_cvt_pkrtz(a, b);
  return __builtin_bit_cast(unsigned, h);
}

// ---------------------------------------------------------------- Phase A (fp16 MFMA)
__global__ __launch_bounds__(256) void xproj_mfma(
    const float* __restrict__ A, const float* __restrict__ W,
    const float* __restrict__ b1, const float* __restrict__ b2,
    __half* __restrict__ C) {
  __shared__ __align__(16) _Float16 As[128 * 72];
  __shared__ __align__(16) _Float16 Bs[128 * 72];
  const int tid = threadIdx.x;
  const int bid = blockIdx.x;
  const int xcd = bid & 7, idx = bid >> 3;
  const int mt = xcd * 32 + (idx >> 4);
  const int nt = idx & 15;
  const int lane = tid & 63;
  const int w = tid >> 6;
  const int wm = w >> 1, wn = w & 1;
  const int fr = lane & 15;
  const int ko = (lane >> 4) * 8;
  const int srow = tid >> 4, sf4 = tid & 15;

  const float* Ab = A + (size_t)(mt * 128) * D_DIM;
  const float* Wb = W + (size_t)(nt * 128) * D_DIM;

  float4v acc[4][4];
#pragma unroll
  for (int m = 0; m < 4; ++m)
#pragma unroll
    for (int n = 0; n < 4; ++n) acc[m][n] = (float4v){0.f, 0.f, 0.f, 0.f};

  for (int k0 = 0; k0 < D_DIM; k0 += 64) {
    float4 aR[8], wR[8];
#pragma unroll
    for (int i = 0; i < 8; ++i) {
      aR[i] = *(const float4*)(Ab + (size_t)(srow + i * 16) * D_DIM + k0 + sf4 * 4);
      wR[i] = *(const float4*)(Wb + (size_t)(srow + i * 16) * D_DIM + k0 + sf4 * 4);
    }
    __syncthreads();
#pragma unroll
    for (int i = 0; i < 8; ++i) {
      int row = srow + i * 16;
      *(uint2*)(As + row * 72 + sf4 * 4) =
          make_uint2(pk2h(aR[i].x, aR[i].y), pk2h(aR[i].z, aR[i].w));
      *(uint2*)(Bs + row * 72 + sf4 * 4) =
          make_uint2(pk2h(wR[i].x, wR[i].y), pk2h(wR[i].z, wR[i].w));
    }
    __syncthreads();
#pragma unroll
    for (int kk = 0; kk < 2; ++kk) {
      half8 af[4], bf[4];
#pragma unroll
      for (int m = 0; m < 4; ++m)
        af[m] = *(const half8*)(As + (wm * 64 + m * 16 + fr) * 72 + kk * 32 + ko);
#pragma unroll
      for (int n = 0; n < 4; ++n)
        bf[n] = *(const half8*)(Bs + (wn * 64 + n * 16 + fr) * 72 + kk * 32 + ko);
#pragma unroll
      for (int m = 0; m < 4; ++m)
#pragma unroll
        for (int n = 0; n < 4; ++n)
          acc[m][n] = __builtin_amdgcn_mfma_f32_16x16x32_f16(af[m], bf[n], acc[m][n], 0, 0, 0);
    }
  }
#pragma unroll
  for (int n = 0; n < 4; ++n) {
    int gcol = nt * 128 + wn * 64 + n * 16 + fr;
    float bias = b1[gcol] + b2[gcol];
#pragma unroll
    for (int m = 0; m < 4; ++m) {
      size_t grow = (size_t)(mt * 128 + wm * 64 + m * 16 + (lane >> 4) * 4);
      __half* cp = C + grow * G_DIM + gcol;
#pragma unroll
      for (int r = 0; r < 4; ++r)
        cp[(size_t)r * G_DIM] = (__half)(acc[m][n][r] + bias);
    }
  }
}

// ---------------------------------------------------------------- Phase B (4 waves/block)
__global__ __launch_bounds__(256, 1) void lstm_seq(
    const __half* __restrict__ xproj, const float* __restrict__ mask,
    const float* __restrict__ h0, const float* __restrict__ Whh,
    float* __restrict__ out, unsigned short* __restrict__ hbuf,
    int* slot_base) {
  __shared__ float part[3 * 128];   // gate f/g/o partials [q-1][b<8][j16]

  const int tid = threadIdx.x;
  const int wv = tid >> 6;         // wave = gate (0=i,1=f,2=g,3=o)
  const int lane = tid & 63;
  const int blk = blockIdx.x;
  const int grp = blk & 7;
  const int rank = blk >> 3;
  const int bbase = grp * 8;
  const int jbase = rank * 16;
  int* slots = (int*)((char*)slot_base + grp * 128);

  const int n = lane & 15;             // j within slice / fragment row
  const int koct = (lane >> 4) * 8;    // k-octet within 32-chunk
  const bool act = lane < 32;          // lanes whose C rows are real batches
  const int g = (lane >> 4) & 1;
  const int jglob = jbase + n;

  // ---- this wave's gate W slice -> 64 VGPRs of B-frags
  half8 w[16];
#pragma unroll
  for (int kc = 0; kc < 16; ++kc) {
    const float* wp = Whh + (size_t)(wv * H_DIM + jbase + n) * H_DIM + kc * 32 + koct;
    float4 lo = *(const float4*)wp;
    float4 hi = *(const float4*)(wp + 4);
    uint4 u = make_uint4(pk2h(lo.x, lo.y), pk2h(lo.z, lo.w),
                         pk2h(hi.x, hi.y), pk2h(hi.z, hi.w));
    w[kc] = __builtin_bit_cast(half8, u);
  }

  // ---- wave0 state: h0/c0, publish h0, flag=1
  int bglob[4];
  float h0v[4] = {0.f, 0.f, 0.f, 0.f}, cval[4] = {0.f, 0.f, 0.f, 0.f};
  float xpv[16], mv[4] = {1.f, 1.f, 1.f, 1.f};
#pragma unroll
  for (int r = 0; r < 4; ++r) xpv[r] = xpv[4 + r] = xpv[8 + r] = xpv[12 + r] = 0.f;
#pragma unroll
  for (int r = 0; r < 4; ++r) bglob[r] = bbase + 4 * g + r;

  if (wv == 0) {
#pragma unroll
    for (int r = 0; r < 4; ++r) {
      h0v[r] = act ? h0[bglob[r] * H_DIM + jglob] : 0.f;
      cval[r] = h0v[r];
    }
#pragma unroll
    for (int r = 0; r < 4; ++r) {
      int mybits = act ? (int)f2h(h0v[r]) : 0;
      int nb = __shfl_down(mybits, 1, 64);
      if (act && !(n & 1))
        AT_ST_U((unsigned*)hbuf + bglob[r] * 256 + (jglob >> 1),
                (unsigned)mybits | ((unsigned)nb << 16));
    }
    __asm__ volatile("s_waitcnt vmcnt(0)" ::: "memory");
    if (tid == 0) AT_ST_I(&slots[rank], 1);
    // prefetch x_proj + mask for ts=0 (overlaps spin)
    if (act) {
#pragma unroll
      for (int r = 0; r < 4; ++r) {
        mv[r] = mask[bglob[r]];
        const __half* xb = xproj + (size_t)bglob[r] * G_DIM + jglob;
#pragma unroll
        for (int q = 0; q < 4; ++q) xpv[q * 4 + r] = (float)xb[q * 512];
      }
    }
  }
  {
    int v;
    do {
      v = (lane < BPG) ? AT_LD_I(&slots[lane]) : 1;
      if (__all(v >= 1)) break;
      __builtin_amdgcn_s_sleep(1);
    } while (true);
  }
  __asm__ volatile("" ::: "memory");

  const size_t arow64 = (size_t)(bbase + (n & 7)) * 128 + (lane >> 4) * 2;  // u64 idx

#pragma unroll 1
  for (int ts = 0; ts < T_DIM; ++ts) {
    const unsigned long long* cur64 =
        (const unsigned long long*)hbuf + (ts & 1) * (B_DIM * H_DIM / 4);
    unsigned* nxt32 = (unsigned*)hbuf + ((ts + 1) & 1) * (B_DIM * H_DIM / 2);

    // A-frags straight from LLC/L2 (producer blocks on same XCD)
    unsigned long long u0[16], u1[16];
    const unsigned long long* ap = cur64 + arow64;
#pragma unroll
    for (int kc = 0; kc < 16; ++kc) {
      u0[kc] = AT_LD64(ap + kc * 8);
      u1[kc] = AT_LD64(ap + kc * 8 + 1);
    }

    // this gate's matmul: 4 independent 4-deep sub-chains over k
    float4v acc[4];
    acc[0] = acc[1] = acc[2] = acc[3] = (float4v){0.f, 0.f, 0.f, 0.f};
#pragma unroll
    for (int kc = 0; kc < 16; ++kc) {
      uint4 ui;
      ui.x = (unsigned)u0[kc];
      ui.y = (unsigned)(u0[kc] >> 32);
      ui.z = (unsigned)u1[kc];
      ui.w = (unsigned)(u1[kc] >> 32);
      half8 a = __builtin_bit_cast(half8, ui);
      acc[kc & 3] = __builtin_amdgcn_mfma_f32_16x16x32_f16(a, w[kc], acc[kc & 3], 0, 0, 0);
    }
    float4v accf = (acc[0] + acc[1]) + (acc[2] + acc[3]);

    // waves 1-3: export partials to LDS (conflict-free pattern)
    if (wv != 0 && act) {
#pragma unroll
      for (int r = 0; r < 4; ++r)
        part[(wv - 1) * 128 + (4 * g + r) * 16 + n] = accf[r];
    }
    __syncthreads();

    if (wv == 0) {
      float hnew[4];
#pragma unroll
      for (int r = 0; r < 4; ++r) {
        int b = 4 * g + r;
        float iv = sigf(accf[r] + xpv[r]);
        float fv = sigf(part[0 * 128 + b * 16 + n] + xpv[4 + r]);
        float gv = tanhfast(part[1 * 128 + b * 16 + n] + xpv[8 + r]);
        float ov = sigf(part[2 * 128 + b * 16 + n] + xpv[12 + r]);
        float cn = fv * cval[r] + iv * gv;
        float hn = ov * tanhfast(cn);
        hn = hn * mv[r] + h0v[r] * (1.f - mv[r]);
        cn = cn * mv[r] + h0v[r] * (1.f - mv[r]);
        cval[r] = cn;
        hnew[r] = hn;
      }
      // publish h_new (packed fp16 pairs, sc1)
#pragma unroll
      for (int r = 0; r < 4; ++r) {
        int mybits = act ? (int)f2h(hnew[r]) : 0;
        int nb = __shfl_down(mybits, 1, 64);
        if (act && !(n & 1))
          AT_ST_U(nxt32 + bglob[r] * 256 + (jglob >> 1),
                  (unsigned)mybits | ((unsigned)nb << 16));
      }
      __asm__ volatile("s_waitcnt vmcnt(0)" ::: "memory");
      if (tid == 0) AT_ST_I(&slots[rank], ts + 2);

      // out stores + next-step prefetch overlap the spin
      if (act) {
#pragma unroll
        for (int r = 0; r < 4; ++r)
          out[((size_t)ts * B_DIM + bglob[r]) * H_DIM + jglob] = hnew[r];
        if (ts == T_DIM - 1) {
#pragma unroll
          for (int r = 0; r < 4; ++r) {
            out[(size_t)T_DIM * B_DIM * H_DIM + bglob[r] * H_DIM + jglob] = hnew[r];
            out[(size_t)T_DIM * B_DIM * H_DIM + B_DIM * H_DIM + bglob[r] * H_DIM + jglob] =
                cval[r];
          }
        } else {
#pragma unroll
          for (int r = 0; r < 4; ++r) {
            mv[r] = mask[(ts + 1) * B_DIM + bglob[r]];
            const __half* xb =
                xproj + ((size_t)(ts + 1) * B_DIM + bglob[r]) * G_DIM + jglob;
#pragma unroll
            for (int q = 0; q < 4; ++q) xpv[q * 4 + r] = (float)xb[q * 512];
          }
        }
      }
    }

    {
      int v;
      do {
        v = (lane < BPG) ? AT_LD_I(&slots[lane]) : (ts + 2);
        if (__all(v >= ts + 2)) break;
        __builtin_amdgcn_s_sleep(1);
      } while (true);
    }
    __asm__ volatile("" ::: "memory");
  }
}

// ---------------------------------------------------------------- launch
extern "C" void kernel_launch(void* const* d_in, const int* in_sizes, int n_in,
                              void* d_out, int out_size, void* d_ws, size_t ws_size,
                              hipStream_t stream) {
  const float* inputs = (const float*)d_in[0];
  const float* maskp  = (const float*)d_in[1];
  const float* h0     = (const float*)d_in[2];
  const float* W_ih   = (const float*)d_in[3];
  const float* W_hh   = (const float*)d_in[4];
  const float* b_ih   = (const float*)d_in[5];
  const float* b_hh   = (const float*)d_in[6];
  float* out = (float*)d_out;

  char* ws = (char*)d_ws;
  int* slot_base = (int*)ws;                            // 8 groups x 32 slots (128B apart)
  unsigned short* hbuf = (unsigned short*)(ws + 4096);  // fp16 h double buffer, 128KB
  __half* xp = (__half*)(ws + 4096 + 2 * (size_t)B_DIM * H_DIM * sizeof(unsigned short));

  (void)hipMemsetAsync(d_ws, 0, 4096, stream);

  xproj_mfma<<<dim3((M_DIM / 128) * (G_DIM / 128)), 256, 0, stream>>>(
      inputs, W_ih, b_ih, b_hh, xp);
  lstm_seq<<<NBLK, 256, 0, stream>>>(xp, maskp, h0, W_hh, out, hbuf, slot_base);

  (void)in_sizes; (void)n_in; (void)out_size; (void)ws_size;
}

// Round 5
// 3515.709 us; speedup vs baseline: 1.3517x; 1.3517x over previous
//
#include <hip/hip_runtime.h>
#include <hip/hip_fp16.h>

// Masked LSTM, T=512 B=64 D=512 H=512.
// Phase A: x_proj = inputs @ W_ih^T + (b_ih + b_hh), fp16 MFMA GEMM, fp16 out.
// Phase B: persistent recurrence, 4 waves/block, gate-per-wave.
//   8 groups (8 batches) x 32 blocks (16 h-dims). Wave q holds gate-q's 16x512
//   W_hh slice as 64 VGPRs of B-frags. h staged ONCE per block per step:
//   256 threads x 4 coalesced u64 LLC loads -> LDS [8][520] f16 (pad -> the
//   round-2-verified conflict-free ds_read_b128 fragment pattern). Each wave
//   MFMAs its gate full-k (4 indep 4-deep chains). Waves 1-3 export partials
//   (128 f32) to LDS; wave 0 does the in-lane epilogue, publishes h (sc1
//   relaxed agent atomics), drains vmcnt, posts the group flag, then issues
//   out[] stores + NEXT-step x_proj/mask prefetch (HBM latency hides under the
//   spin). part[]/hl reuse race-free via flag ordering (waves re-enter staging
//   only after every rank's wave0 posted, which follows its reads).

#define T_DIM 512
#define B_DIM 64
#define D_DIM 512
#define H_DIM 512
#define G_DIM 2048
#define M_DIM (T_DIM * B_DIM)

#define NGROUP 8
#define BPG 32
#define NBLK (NGROUP * BPG)     // 256
#define WS 520                  // LDS row stride in fp16 elements (512 + 8 pad)

typedef __attribute__((ext_vector_type(8))) _Float16 half8;
typedef __attribute__((ext_vector_type(2))) __fp16 fp16x2;
typedef __attribute__((ext_vector_type(4))) float float4v;

#define AT_LD_U(p)    __hip_atomic_load((p), __ATOMIC_RELAXED, __HIP_MEMORY_SCOPE_AGENT)
#define AT_ST_U(p, v) __hip_atomic_store((p), (v), __ATOMIC_RELAXED, __HIP_MEMORY_SCOPE_AGENT)
#define AT_LD_I(p)    __hip_atomic_load((p), __ATOMIC_RELAXED, __HIP_MEMORY_SCOPE_AGENT)
#define AT_ST_I(p, v) __hip_atomic_store((p), (v), __ATOMIC_RELAXED, __HIP_MEMORY_SCOPE_AGENT)
#define AT_LD64(p)    __hip_atomic_load((p), __ATOMIC_RELAXED, __HIP_MEMORY_SCOPE_AGENT)

__device__ __forceinline__ float sigf(float x) { return 1.0f / (1.0f + __expf(-x)); }
__device__ __forceinline__ float tanhfast(float x) { return 2.0f / (1.0f + __expf(-2.0f * x)) - 1.0f; }
__device__ __forceinline__ unsigned short f2h(float x) {
  return __builtin_bit_cast(unsigned short, (_Float16)x);
}
__device__ __forceinline__ unsigned pk2h(float a, float b) {
  fp16x2 h = __builtin_amdgcn_cvt_pkrtz(a, b);
  return __builtin_bit_cast(unsigned, h);
}

// ---------------------------------------------------------------- Phase A (fp16 MFMA)
__global__ __launch_bounds__(256) void xproj_mfma(
    const float* __restrict__ A, const float* __restrict__ W,
    const float* __restrict__ b1, const float* __restrict__ b2,
    __half* __restrict__ C) {
  __shared__ __align__(16) _Float16 As[128 * 72];
  __shared__ __align__(16) _Float16 Bs[128 * 72];
  const int tid = threadIdx.x;
  const int bid = blockIdx.x;
  const int xcd = bid & 7, idx = bid >> 3;
  const int mt = xcd * 32 + (idx >> 4);
  const int nt = idx & 15;
  const int lane = tid & 63;
  const int w = tid >> 6;
  const int wm = w >> 1, wn = w & 1;
  const int fr = lane & 15;
  const int ko = (lane >> 4) * 8;
  const int srow = tid >> 4, sf4 = tid & 15;

  const float* Ab = A + (size_t)(mt * 128) * D_DIM;
  const float* Wb = W + (size_t)(nt * 128) * D_DIM;

  float4v acc[4][4];
#pragma unroll
  for (int m = 0; m < 4; ++m)
#pragma unroll
    for (int n = 0; n < 4; ++n) acc[m][n] = (float4v){0.f, 0.f, 0.f, 0.f};

  for (int k0 = 0; k0 < D_DIM; k0 += 64) {
    float4 aR[8], wR[8];
#pragma unroll
    for (int i = 0; i < 8; ++i) {
      aR[i] = *(const float4*)(Ab + (size_t)(srow + i * 16) * D_DIM + k0 + sf4 * 4);
      wR[i] = *(const float4*)(Wb + (size_t)(srow + i * 16) * D_DIM + k0 + sf4 * 4);
    }
    __syncthreads();
#pragma unroll
    for (int i = 0; i < 8; ++i) {
      int row = srow + i * 16;
      *(uint2*)(As + row * 72 + sf4 * 4) =
          make_uint2(pk2h(aR[i].x, aR[i].y), pk2h(aR[i].z, aR[i].w));
      *(uint2*)(Bs + row * 72 + sf4 * 4) =
          make_uint2(pk2h(wR[i].x, wR[i].y), pk2h(wR[i].z, wR[i].w));
    }
    __syncthreads();
#pragma unroll
    for (int kk = 0; kk < 2; ++kk) {
      half8 af[4], bf[4];
#pragma unroll
      for (int m = 0; m < 4; ++m)
        af[m] = *(const half8*)(As + (wm * 64 + m * 16 + fr) * 72 + kk * 32 + ko);
#pragma unroll
      for (int n = 0; n < 4; ++n)
        bf[n] = *(const half8*)(Bs + (wn * 64 + n * 16 + fr) * 72 + kk * 32 + ko);
#pragma unroll
      for (int m = 0; m < 4; ++m)
#pragma unroll
        for (int n = 0; n < 4; ++n)
          acc[m][n] = __builtin_amdgcn_mfma_f32_16x16x32_f16(af[m], bf[n], acc[m][n], 0, 0, 0);
    }
  }
#pragma unroll
  for (int n = 0; n < 4; ++n) {
    int gcol = nt * 128 + wn * 64 + n * 16 + fr;
    float bias = b1[gcol] + b2[gcol];
#pragma unroll
    for (int m = 0; m < 4; ++m) {
      size_t grow = (size_t)(mt * 128 + wm * 64 + m * 16 + (lane >> 4) * 4);
      __half* cp = C + grow * G_DIM + gcol;
#pragma unroll
      for (int r = 0; r < 4; ++r)
        cp[(size_t)r * G_DIM] = (__half)(acc[m][n][r] + bias);
    }
  }
}

// ---------------------------------------------------------------- Phase B (4 waves/block)
__global__ __launch_bounds__(256) void lstm_seq(
    const __half* __restrict__ xproj, const float* __restrict__ mask,
    const float* __restrict__ h0, const float* __restrict__ Whh,
    float* __restrict__ out, unsigned short* __restrict__ hbuf,
    int* slot_base) {
  __shared__ __align__(16) unsigned short hl[8 * WS];  // staged h [b][k], 8320 B
  __shared__ float part[3 * 128];                      // f/g/o partials [q-1][b][j16]

  const int tid = threadIdx.x;
  const int wv = tid >> 6;         // wave = gate (0=i,1=f,2=g,3=o)
  const int lane = tid & 63;
  const int blk = blockIdx.x;
  const int grp = blk & 7;
  const int rank = blk >> 3;
  const int bbase = grp * 8;
  const int jbase = rank * 16;
  int* slots = (int*)((char*)slot_base + grp * 128);

  const int n = lane & 15;             // j within slice / B-fragment row
  const int koct = (lane >> 4) * 8;    // k-octet within 32-chunk
  const bool act = lane < 32;          // lanes whose C rows are real batches
  const int g = (lane >> 4) & 1;
  const int jglob = jbase + n;

  // ---- this wave's gate W slice -> 64 VGPRs of B-frags
  half8 w[16];
#pragma unroll
  for (int kc = 0; kc < 16; ++kc) {
    const float* wp = Whh + (size_t)(wv * H_DIM + jbase + n) * H_DIM + kc * 32 + koct;
    float4 lo = *(const float4*)wp;
    float4 hi = *(const float4*)(wp + 4);
    uint4 u = make_uint4(pk2h(lo.x, lo.y), pk2h(lo.z, lo.w),
                         pk2h(hi.x, hi.y), pk2h(hi.z, hi.w));
    w[kc] = __builtin_bit_cast(half8, u);
  }

  // ---- wave0 recurrent state
  int bglob[4];
  float h0v[4] = {0.f, 0.f, 0.f, 0.f}, cval[4] = {0.f, 0.f, 0.f, 0.f};
  float xpv[16], mv[4] = {1.f, 1.f, 1.f, 1.f};
#pragma unroll
  for (int i = 0; i < 16; ++i) xpv[i] = 0.f;
#pragma unroll
  for (int r = 0; r < 4; ++r) bglob[r] = bbase + 4 * g + r;

  if (wv == 0) {
#pragma unroll
    for (int r = 0; r < 4; ++r) {
      h0v[r] = act ? h0[bglob[r] * H_DIM + jglob] : 0.f;
      cval[r] = h0v[r];
    }
    // publish h0 into buffer 0 (packed fp16 pairs; even-n lanes store)
#pragma unroll
    for (int r = 0; r < 4; ++r) {
      int mybits = act ? (int)f2h(h0v[r]) : 0;
      int nb = __shfl_down(mybits, 1, 64);
      if (act && !(n & 1))
        AT_ST_U((unsigned*)hbuf + bglob[r] * 256 + (jglob >> 1),
                (unsigned)mybits | ((unsigned)nb << 16));
    }
    __asm__ volatile("s_waitcnt vmcnt(0)" ::: "memory");
    if (tid == 0) AT_ST_I(&slots[rank], 1);
    // prefetch x_proj + mask for ts=0 (overlaps the spin)
    if (act) {
#pragma unroll
      for (int r = 0; r < 4; ++r) {
        mv[r] = mask[bglob[r]];
        const __half* xb = xproj + (size_t)bglob[r] * G_DIM + jglob;
#pragma unroll
        for (int q = 0; q < 4; ++q) xpv[q * 4 + r] = (float)xb[q * 512];
      }
    }
  }
  {
    int v;
    do {
      v = (lane < BPG) ? AT_LD_I(&slots[lane]) : 1;
      if (__all(v >= 1)) break;
      __builtin_amdgcn_s_sleep(1);
    } while (true);
  }
  __asm__ volatile("" ::: "memory");

#pragma unroll 1
  for (int ts = 0; ts < T_DIM; ++ts) {
    const unsigned long long* cur64 =
        (const unsigned long long*)hbuf + (ts & 1) * (B_DIM * H_DIM / 4) +
        (size_t)bbase * 128;
    unsigned* nxt32 = (unsigned*)hbuf + ((ts + 1) & 1) * (B_DIM * H_DIM / 2);

    // ---- coalesced stage: 8 KB group h slab -> LDS [8][520] (256 thr x 4 u64)
#pragma unroll
    for (int j = 0; j < 4; ++j) {
      int v = tid * 4 + j;                    // u64 index, contiguous
      unsigned long long u = AT_LD64(cur64 + v);
      ((unsigned long long*)hl)[(v >> 7) * 130 + (v & 127)] = u;
    }
    __syncthreads();

    // ---- this gate's matmul: frags from LDS (conflict-free), 4 indep chains
    float4v acc[4];
    acc[0] = acc[1] = acc[2] = acc[3] = (float4v){0.f, 0.f, 0.f, 0.f};
#pragma unroll
    for (int kc = 0; kc < 16; ++kc) {
      half8 a = *(const half8*)((const _Float16*)hl + (lane & 7) * WS + kc * 32 + koct);
      acc[kc & 3] = __builtin_amdgcn_mfma_f32_16x16x32_f16(a, w[kc], acc[kc & 3], 0, 0, 0);
    }
    float4v accf = (acc[0] + acc[1]) + (acc[2] + acc[3]);

    // waves 1-3: export partials
    if (wv != 0 && act) {
#pragma unroll
      for (int r = 0; r < 4; ++r)
        part[(wv - 1) * 128 + (4 * g + r) * 16 + n] = accf[r];
    }
    __syncthreads();

    if (wv == 0) {
      float hnew[4];
#pragma unroll
      for (int r = 0; r < 4; ++r) {
        int b = 4 * g + r;
        float iv = sigf(accf[r] + xpv[r]);
        float fv = sigf(part[0 * 128 + b * 16 + n] + xpv[4 + r]);
        float gv = tanhfast(part[1 * 128 + b * 16 + n] + xpv[8 + r]);
        float ov = sigf(part[2 * 128 + b * 16 + n] + xpv[12 + r]);
        float cn = fv * cval[r] + iv * gv;
        float hn = ov * tanhfast(cn);
        hn = hn * mv[r] + h0v[r] * (1.f - mv[r]);
        cn = cn * mv[r] + h0v[r] * (1.f - mv[r]);
        cval[r] = cn;
        hnew[r] = hn;
      }
      // publish h_new (packed fp16 pairs, sc1)
#pragma unroll
      for (int r = 0; r < 4; ++r) {
        int mybits = act ? (int)f2h(hnew[r]) : 0;
        int nb = __shfl_down(mybits, 1, 64);
        if (act && !(n & 1))
          AT_ST_U(nxt32 + bglob[r] * 256 + (jglob >> 1),
                  (unsigned)mybits | ((unsigned)nb << 16));
      }
      __asm__ volatile("s_waitcnt vmcnt(0)" ::: "memory");
      if (tid == 0) AT_ST_I(&slots[rank], ts + 2);

      // out stores + NEXT-step prefetch overlap the spin
      if (act) {
#pragma unroll
        for (int r = 0; r < 4; ++r)
          out[((size_t)ts * B_DIM + bglob[r]) * H_DIM + jglob] = hnew[r];
        if (ts == T_DIM - 1) {
#pragma unroll
          for (int r = 0; r < 4; ++r) {
            out[(size_t)T_DIM * B_DIM * H_DIM + bglob[r] * H_DIM + jglob] = hnew[r];
            out[(size_t)T_DIM * B_DIM * H_DIM + B_DIM * H_DIM + bglob[r] * H_DIM + jglob] =
                cval[r];
          }
        } else {
#pragma unroll
          for (int r = 0; r < 4; ++r) {
            mv[r] = mask[(ts + 1) * B_DIM + bglob[r]];
            const __half* xb =
                xproj + ((size_t)(ts + 1) * B_DIM + bglob[r]) * G_DIM + jglob;
#pragma unroll
            for (int q = 0; q < 4; ++q) xpv[q * 4 + r] = (float)xb[q * 512];
          }
        }
      }
    }

    {
      int v;
      do {
        v = (lane < BPG) ? AT_LD_I(&slots[lane]) : (ts + 2);
        if (__all(v >= ts + 2)) break;
        __builtin_amdgcn_s_sleep(1);
      } while (true);
    }
    __asm__ volatile("" ::: "memory");
  }
}

// ---------------------------------------------------------------- launch
extern "C" void kernel_launch(void* const* d_in, const int* in_sizes, int n_in,
                              void* d_out, int out_size, void* d_ws, size_t ws_size,
                              hipStream_t stream) {
  const float* inputs = (const float*)d_in[0];
  const float* maskp  = (const float*)d_in[1];
  const float* h0     = (const float*)d_in[2];
  const float* W_ih   = (const float*)d_in[3];
  const float* W_hh   = (const float*)d_in[4];
  const float* b_ih   = (const float*)d_in[5];
  const float* b_hh   = (const float*)d_in[6];
  float* out = (float*)d_out;

  char* ws = (char*)d_ws;
  int* slot_base = (int*)ws;                            // 8 groups x 32 slots (128B apart)
  unsigned short* hbuf = (unsigned short*)(ws + 4096);  // fp16 h double buffer, 128KB
  __half* xp = (__half*)(ws + 4096 + 2 * (size_t)B_DIM * H_DIM * sizeof(unsigned short));

  (void)hipMemsetAsync(d_ws, 0, 4096, stream);

  xproj_mfma<<<dim3((M_DIM / 128) * (G_DIM / 128)), 256, 0, stream>>>(
      inputs, W_ih, b_ih, b_hh, xp);
  lstm_seq<<<NBLK, 256, 0, stream>>>(xp, maskp, h0, W_hh, out, hbuf, slot_base);

  (void)in_sizes; (void)n_in; (void)out_size; (void)ws_size;
}

// Round 6
// 1489.178 us; speedup vs baseline: 3.1911x; 2.3608x over previous
//
#include <hip/hip_runtime.h>
#include <hip/hip_fp16.h>

// Masked LSTM, T=512 B=64 D=512 H=512.
// Phase A: x_proj = inputs @ W_ih^T + (b_ih + b_hh), fp16 MFMA GEMM, fp16 out.
// Phase B: round-2-verified structure (8 waves/512 thr, W_hh fp16 in LDS, 4 gate
//   tiles x 2 k-splits, coalesced LDS staging of h, tid<64 flag spin) with three
//   surgical critical-path edits:
//   (1) out[] stores + next-step x_proj/mask prefetch moved AFTER the flag post
//       (HBM latency hides under the spin instead of the pre-flag vmcnt drain).
//   (2) gl reduce stage + 1 barrier removed: epilogue threads sum the two
//       k-split partials straight from part[] (conflict-free reads).
//   (3) u64 staging (2 loads/thread, conflict-free) and u64 publish (32 stores
//       instead of 64 -> half the drain transactions).

#define T_DIM 512
#define B_DIM 64
#define D_DIM 512
#define H_DIM 512
#define G_DIM 2048
#define M_DIM (T_DIM * B_DIM)

#define NGROUP 8
#define BPG 32
#define NBLK (NGROUP * BPG)     // 256
#define NTHR 512
#define WS 520                  // LDS row stride in fp16 elements (512 + 8 pad)

typedef __attribute__((ext_vector_type(8))) _Float16 half8;
typedef __attribute__((ext_vector_type(2))) __fp16 fp16x2;
typedef __attribute__((ext_vector_type(4))) float float4v;

#define AT_LD_U(p)    __hip_atomic_load((p), __ATOMIC_RELAXED, __HIP_MEMORY_SCOPE_AGENT)
#define AT_ST_U(p, v) __hip_atomic_store((p), (v), __ATOMIC_RELAXED, __HIP_MEMORY_SCOPE_AGENT)
#define AT_LD_I(p)    __hip_atomic_load((p), __ATOMIC_RELAXED, __HIP_MEMORY_SCOPE_AGENT)
#define AT_ST_I(p, v) __hip_atomic_store((p), (v), __ATOMIC_RELAXED, __HIP_MEMORY_SCOPE_AGENT)
#define AT_LD64(p)    __hip_atomic_load((p), __ATOMIC_RELAXED, __HIP_MEMORY_SCOPE_AGENT)
#define AT_ST64(p, v) __hip_atomic_store((p), (v), __ATOMIC_RELAXED, __HIP_MEMORY_SCOPE_AGENT)

__device__ __forceinline__ float sigf(float x) { return 1.0f / (1.0f + __expf(-x)); }
__device__ __forceinline__ float tanhfast(float x) { return 2.0f / (1.0f + __expf(-2.0f * x)) - 1.0f; }
__device__ __forceinline__ unsigned short f2h(float x) {
  return __builtin_bit_cast(unsigned short, (_Float16)x);
}
__device__ __forceinline__ unsigned pk2h(float a, float b) {
  fp16x2 h = __builtin_amdgcn_cvt_pkrtz(a, b);
  return __builtin_bit_cast(unsigned, h);
}

// ---------------------------------------------------------------- Phase A (fp16 MFMA)
__global__ __launch_bounds__(256) void xproj_mfma(
    const float* __restrict__ A, const float* __restrict__ W,
    const float* __restrict__ b1, const float* __restrict__ b2,
    __half* __restrict__ C) {
  __shared__ __align__(16) _Float16 As[128 * 72];
  __shared__ __align__(16) _Float16 Bs[128 * 72];
  const int tid = threadIdx.x;
  const int bid = blockIdx.x;
  const int xcd = bid & 7, idx = bid >> 3;
  const int mt = xcd * 32 + (idx >> 4);
  const int nt = idx & 15;
  const int lane = tid & 63;
  const int w = tid >> 6;
  const int wm = w >> 1, wn = w & 1;
  const int fr = lane & 15;
  const int ko = (lane >> 4) * 8;
  const int srow = tid >> 4, sf4 = tid & 15;

  const float* Ab = A + (size_t)(mt * 128) * D_DIM;
  const float* Wb = W + (size_t)(nt * 128) * D_DIM;

  float4v acc[4][4];
#pragma unroll
  for (int m = 0; m < 4; ++m)
#pragma unroll
    for (int n = 0; n < 4; ++n) acc[m][n] = (float4v){0.f, 0.f, 0.f, 0.f};

  for (int k0 = 0; k0 < D_DIM; k0 += 64) {
    float4 aR[8], wR[8];
#pragma unroll
    for (int i = 0; i < 8; ++i) {
      aR[i] = *(const float4*)(Ab + (size_t)(srow + i * 16) * D_DIM + k0 + sf4 * 4);
      wR[i] = *(const float4*)(Wb + (size_t)(srow + i * 16) * D_DIM + k0 + sf4 * 4);
    }
    __syncthreads();
#pragma unroll
    for (int i = 0; i < 8; ++i) {
      int row = srow + i * 16;
      *(uint2*)(As + row * 72 + sf4 * 4) =
          make_uint2(pk2h(aR[i].x, aR[i].y), pk2h(aR[i].z, aR[i].w));
      *(uint2*)(Bs + row * 72 + sf4 * 4) =
          make_uint2(pk2h(wR[i].x, wR[i].y), pk2h(wR[i].z, wR[i].w));
    }
    __syncthreads();
#pragma unroll
    for (int kk = 0; kk < 2; ++kk) {
      half8 af[4], bf[4];
#pragma unroll
      for (int m = 0; m < 4; ++m)
        af[m] = *(const half8*)(As + (wm * 64 + m * 16 + fr) * 72 + kk * 32 + ko);
#pragma unroll
      for (int n = 0; n < 4; ++n)
        bf[n] = *(const half8*)(Bs + (wn * 64 + n * 16 + fr) * 72 + kk * 32 + ko);
#pragma unroll
      for (int m = 0; m < 4; ++m)
#pragma unroll
        for (int n = 0; n < 4; ++n)
          acc[m][n] = __builtin_amdgcn_mfma_f32_16x16x32_f16(af[m], bf[n], acc[m][n], 0, 0, 0);
    }
  }
#pragma unroll
  for (int n = 0; n < 4; ++n) {
    int gcol = nt * 128 + wn * 64 + n * 16 + fr;
    float bias = b1[gcol] + b2[gcol];
#pragma unroll
    for (int m = 0; m < 4; ++m) {
      size_t grow = (size_t)(mt * 128 + wm * 64 + m * 16 + (lane >> 4) * 4);
      __half* cp = C + grow * G_DIM + gcol;
#pragma unroll
      for (int r = 0; r < 4; ++r)
        cp[(size_t)r * G_DIM] = (__half)(acc[m][n][r] + bias);
    }
  }
}

// ---------------------------------------------------------------- Phase B
__global__ __launch_bounds__(NTHR) void lstm_seq(
    const __half* __restrict__ xproj, const float* __restrict__ mask,
    const float* __restrict__ h0, const float* __restrict__ Whh,
    float* __restrict__ out, unsigned short* __restrict__ hbuf,
    int* slot_base) {
  extern __shared__ char smemc[];
  unsigned short* Wl = (unsigned short*)smemc;     // [r][k] 64 x WS f16 = 66560 B
  unsigned short* hl = Wl + 64 * WS;               // [m][k] 16 x WS f16 = 16640 B (m>=8 garbage)
  float* part = (float*)(hl + 16 * WS);            // 8 waves x 256 f32 = 8192 B

  const int tid = threadIdx.x;
  const int blk = blockIdx.x;
  const int grp = blk & 7;
  const int rank = blk >> 3;
  const int bbase = grp * 8;
  const int jbase = rank * 16;
  int* slots = (int*)((char*)slot_base + grp * 128);

  // W_hh slice -> LDS fp16. r = q*16 + jl <-> global row q*512 + jbase + jl.
  for (int idx = tid; idx < 64 * 128; idx += NTHR) {
    int r = idx >> 7;
    int k4 = (idx & 127) << 2;
    int grow = (r >> 4) * H_DIM + jbase + (r & 15);
    float4 wv = *(const float4*)(Whh + (size_t)grow * H_DIM + k4);
    *(uint2*)(Wl + r * WS + k4) = make_uint2(pk2h(wv.x, wv.y), pk2h(wv.z, wv.w));
  }

  const int eb = tid >> 4, ejl = tid & 15;   // tid<128: (batch 0..7, h-dim 0..15)
  const int bglob = bbase + eb;
  const int jglob = jbase + ejl;
  float h0v = 0.0f, cval = 0.0f;
  float xpv0 = 0.f, xpv1 = 0.f, xpv2 = 0.f, xpv3 = 0.f, mval = 1.f;
  if (tid < 128) {
    h0v = h0[bglob * H_DIM + jglob];
    cval = h0v;
  }

  // publish h0 as u64 (4 packed fp16) into buffer 0
  {
    int mybits = (tid < 128) ? (int)f2h(h0v) : 0;
    int nb1 = __shfl_down(mybits, 1, 64);
    int nb2 = __shfl_down(mybits, 2, 64);
    int nb3 = __shfl_down(mybits, 3, 64);
    if (tid < 128 && ((ejl & 3) == 0)) {
      unsigned lo = (unsigned)mybits | ((unsigned)nb1 << 16);
      unsigned hi = (unsigned)nb2 | ((unsigned)nb3 << 16);
      AT_ST64((unsigned long long*)hbuf + bglob * 128 + (jglob >> 2),
              ((unsigned long long)hi << 32) | lo);
    }
  }
  __syncthreads();   // drains vmcnt(0): publishes at coherence point
  if (tid == 0) AT_ST_I(&slots[rank], 1);
  // prefetch x_proj + mask for ts=0 under the spin
  if (tid < 128) {
    mval = mask[bglob];
    const __half* xb = xproj + (size_t)bglob * G_DIM + jglob;
    xpv0 = (float)xb[0];
    xpv1 = (float)xb[512];
    xpv2 = (float)xb[1024];
    xpv3 = (float)xb[1536];
  }
  if (tid < 64) {
    int v;
    do {
      v = (tid < BPG) ? AT_LD_I(&slots[tid]) : 1;
      if (__all(v >= 1)) break;
      __builtin_amdgcn_s_sleep(2);
    } while (true);
  }
  __syncthreads();
  __asm__ volatile("" ::: "memory");

  const int w = tid >> 6;        // wave id
  const int lane = tid & 63;
  const int q = w & 3;           // gate tile (i,f,g,o)
  const int ks = w >> 2;         // k-split 0..1 (256 k each)
  const int am = lane & 15;      // A row (batch, padded to 16)
  const int koct = (lane >> 4) * 8;
  const int br = q * 16 + (lane & 15);   // W row in LDS

  for (int ts = 0; ts < T_DIM; ++ts) {
    const unsigned long long* cur64 =
        (const unsigned long long*)hbuf + (ts & 1) * (B_DIM * H_DIM / 4) +
        (size_t)bbase * 128;
    unsigned long long* nxt64 =
        (unsigned long long*)hbuf + ((ts + 1) & 1) * (B_DIM * H_DIM / 4);

    // stage h (8 batches x 512 f16 = 8KB): 512 thr x 2 coalesced u64, LDS [8][520]
#pragma unroll
    for (int i = 0; i < 2; ++i) {
      int v = tid + i * NTHR;                       // u64 index 0..1023
      unsigned long long u = AT_LD64(cur64 + v);
      ((unsigned long long*)hl)[(v >> 7) * 130 + (v & 127)] = u;
    }
    __syncthreads();

    // MFMA: D[m][n] = sum_k h[m][k] * W[q*16+n][k] over this wave's 256-k slice
    float4v acc = {0.f, 0.f, 0.f, 0.f};
#pragma unroll
    for (int kc = 0; kc < 8; ++kc) {
      int k = ks * 256 + kc * 32 + koct;
      half8 a = *(const half8*)((const _Float16*)hl + am * WS + k);
      half8 b8 = *(const half8*)((const _Float16*)Wl + br * WS + k);
      acc = __builtin_amdgcn_mfma_f32_16x16x32_f16(a, b8, acc, 0, 0, 0);
    }
    // partials -> LDS: part[w][m][n]
#pragma unroll
    for (int reg = 0; reg < 4; ++reg) {
      int m = (lane >> 4) * 4 + reg;
      part[w * 256 + m * 16 + (lane & 15)] = acc[reg];
    }
    __syncthreads();

    // epilogue (tid<128): sum the two k-splits straight from part[]
    float hnew = 0.f;
    if (tid < 128) {
      int o = eb * 16 + ejl;
      float iv = sigf(part[0 * 256 + o] + part[4 * 256 + o] + xpv0);
      float fv = sigf(part[1 * 256 + o] + part[5 * 256 + o] + xpv1);
      float gv = tanhfast(part[2 * 256 + o] + part[6 * 256 + o] + xpv2);
      float ov = sigf(part[3 * 256 + o] + part[7 * 256 + o] + xpv3);
      float cn = fv * cval + iv * gv;
      float hn = ov * tanhfast(cn);
      hnew = hn * mval + h0v * (1.0f - mval);
      cval = cn * mval + h0v * (1.0f - mval);
    }
    // publish h_new as u64 (4 packed fp16)
    {
      int mybits = (tid < 128) ? (int)f2h(hnew) : 0;
      int nb1 = __shfl_down(mybits, 1, 64);
      int nb2 = __shfl_down(mybits, 2, 64);
      int nb3 = __shfl_down(mybits, 3, 64);
      if (tid < 128 && ((ejl & 3) == 0)) {
        unsigned lo = (unsigned)mybits | ((unsigned)nb1 << 16);
        unsigned hi = (unsigned)nb2 | ((unsigned)nb3 << 16);
        AT_ST64(nxt64 + bglob * 128 + (jglob >> 2),
                ((unsigned long long)hi << 32) | lo);
      }
    }
    __syncthreads();   // per-wave vmcnt drain -> publishes visible before flag
    if (tid == 0) AT_ST_I(&slots[rank], ts + 2);

    // out stores + NEXT-step prefetch in the spin shadow
    if (tid < 128) {
      out[((size_t)ts * B_DIM + bglob) * H_DIM + jglob] = hnew;
      if (ts == T_DIM - 1) {
        out[(size_t)T_DIM * B_DIM * H_DIM + bglob * H_DIM + jglob] = hnew;
        out[(size_t)T_DIM * B_DIM * H_DIM + B_DIM * H_DIM + bglob * H_DIM + jglob] = cval;
      } else {
        mval = mask[(ts + 1) * B_DIM + bglob];
        const __half* xb = xproj + ((size_t)(ts + 1) * B_DIM + bglob) * G_DIM + jglob;
        xpv0 = (float)xb[0];
        xpv1 = (float)xb[512];
        xpv2 = (float)xb[1024];
        xpv3 = (float)xb[1536];
      }
    }

    if (tid < 64) {
      int v;
      do {
        v = (tid < BPG) ? AT_LD_I(&slots[tid]) : (ts + 2);
        if (__all(v >= ts + 2)) break;
        __builtin_amdgcn_s_sleep(2);
      } while (true);
    }
    __syncthreads();
    __asm__ volatile("" ::: "memory");
  }
}

// ---------------------------------------------------------------- launch
extern "C" void kernel_launch(void* const* d_in, const int* in_sizes, int n_in,
                              void* d_out, int out_size, void* d_ws, size_t ws_size,
                              hipStream_t stream) {
  const float* inputs = (const float*)d_in[0];
  const float* maskp  = (const float*)d_in[1];
  const float* h0     = (const float*)d_in[2];
  const float* W_ih   = (const float*)d_in[3];
  const float* W_hh   = (const float*)d_in[4];
  const float* b_ih   = (const float*)d_in[5];
  const float* b_hh   = (const float*)d_in[6];
  float* out = (float*)d_out;

  char* ws = (char*)d_ws;
  int* slot_base = (int*)ws;                            // 8 groups x 32 slots (128B apart)
  unsigned short* hbuf = (unsigned short*)(ws + 4096);  // fp16 h double buffer, 128KB
  __half* xp = (__half*)(ws + 4096 + 2 * (size_t)B_DIM * H_DIM * sizeof(unsigned short));

  (void)hipMemsetAsync(d_ws, 0, 4096, stream);

  size_t ldsB = (size_t)(64 * WS * 2 + 16 * WS * 2 + 2048 * 4);  // 91392 B

  xproj_mfma<<<dim3((M_DIM / 128) * (G_DIM / 128)), 256, 0, stream>>>(
      inputs, W_ih, b_ih, b_hh, xp);
  lstm_seq<<<NBLK, NTHR, ldsB, stream>>>(xp, maskp, h0, W_hh, out, hbuf, slot_base);

  (void)in_sizes; (void)n_in; (void)out_size; (void)ws_size;
}